// Round 10
// baseline (300.819 us; speedup 1.0000x reference)
//
#include <hip/hip_runtime.h>

#define DIM     128
#define NAGENT  100
#define NAP     112          // agents padded to 7x16 MFMA n-tiles
#define NCITY   5000
#define NBATCH  64
#define NA_PAD  101
#define SUSP_CAP 16384
#define EPS     2e-3f

#define CPB     128                        // cities per tile (K3)
#define CTILES  ((NCITY + CPB - 1) / CPB)  // 40
#define NT      5                          // tiles per block
#define BPB     8                          // blocks per batch (8*5 = 40 tiles)
#define FRAG_PB 14336                      // bf16 elems per batch per buffer (hi or lo)
#define CHUNKS  3584                       // 16-B chunks per batch (hi+lo)

// ---- workspace layout (bytes), total 7,012,864 ----
#define OFF_CNT 0
#define OFF_SUS 512                        // 64 KB suspect list
#define OFF_KP  66048                      // fp32 k [64][100][128] = 3,276,800
#define OFF_GF  3342848                    // bf16 Gfrag [64][ hi 14336 | lo 14336 ]

typedef __attribute__((ext_vector_type(8))) short short8;
typedef __attribute__((ext_vector_type(4))) float f32x4;

__device__ __forceinline__ unsigned short bf16_rne(float x) {
    unsigned u = __float_as_uint(x);
    u += 0x7FFFu + ((u >> 16) & 1u);
    return (unsigned short)(u >> 16);
}
__device__ __forceinline__ float bf16_tof(unsigned short h) {
    return __uint_as_float(((unsigned)h) << 16);
}

// ---------------------------------------------------------------------------
// K1: k32[b][a][e] = sum_d agent[b][a][d] * Wk[d][e]  (fp32 accum, 4-way ILP)
// Also zeroes the suspect counter (K1 -> K3 stream ordering makes this safe).
// ---------------------------------------------------------------------------
__global__ __launch_bounds__(128) void proj_k_kernel(const float* __restrict__ agent,
                                                     const float* __restrict__ Wk,
                                                     float* __restrict__ kp32,
                                                     int* __restrict__ counter) {
    const int ba = blockIdx.x;
    const int e  = threadIdx.x;

    if (ba == 0 && e == 0) *counter = 0;

    __shared__ float s_a[DIM];
    s_a[e] = agent[(size_t)ba * DIM + e];
    __syncthreads();

    float a0 = 0.f, a1 = 0.f, a2 = 0.f, a3 = 0.f;
    #pragma unroll 8
    for (int d = 0; d < DIM; d += 4) {
        a0 = fmaf(s_a[d + 0], Wk[(d + 0) * DIM + e], a0);
        a1 = fmaf(s_a[d + 1], Wk[(d + 1) * DIM + e], a1);
        a2 = fmaf(s_a[d + 2], Wk[(d + 2) * DIM + e], a2);
        a3 = fmaf(s_a[d + 3], Wk[(d + 3) * DIM + e], a3);
    }
    kp32[(size_t)ba * DIM + e] = (a0 + a1) + (a2 + a3);
}

// ---------------------------------------------------------------------------
// K2: G[b][a][d] = sum_e Wq[d][e] * k32[b][a][e] (fp32 accum, 4-way ILP),
// emitted as split bf16 (hi RNE + lo RNE) in MFMA-FRAGMENT ORDER:
//   t=a>>4, col=a&15, ks=d>>5, kgrp=(d>>3)&3, j=d&7, lane=kgrp*16+col
//   fidx = ((t*4+ks)*64 + lane)*8 + j;  pad agents [100,112) = 0.
// ---------------------------------------------------------------------------
__global__ __launch_bounds__(256) void gmat_kernel(const float* __restrict__ Wq,
                                                   const float* __restrict__ kp32,
                                                   unsigned short* __restrict__ Gf) {
    const int b      = blockIdx.x >> 3;
    const int dchunk = blockIdx.x & 7;
    const int tid    = threadIdx.x;

    __shared__ float s_kp[DIM][NA_PAD];   // [e][a]

    const float* kpb = kp32 + (size_t)b * NAGENT * DIM;
    for (int i = tid; i < NAGENT * DIM; i += 256) {
        int a = i >> 7;
        int e = i & 127;
        s_kp[e][a] = kpb[i];
    }
    __syncthreads();

    unsigned short* GfB = Gf + (size_t)b * (2 * FRAG_PB);
    const int d0 = dchunk * 16;
    for (int i = tid; i < 16 * NAP; i += 256) {   // 1792
        int dl = i / NAP;
        int a  = i - dl * NAP;
        int d  = d0 + dl;
        unsigned short hi = 0, lo = 0;
        if (a < NAGENT) {
            const float* wq = Wq + d * DIM;
            float q0 = 0.f, q1 = 0.f, q2 = 0.f, q3 = 0.f;
            #pragma unroll 8
            for (int e = 0; e < DIM; e += 4) {
                q0 = fmaf(wq[e + 0], s_kp[e + 0][a], q0);
                q1 = fmaf(wq[e + 1], s_kp[e + 1][a], q1);
                q2 = fmaf(wq[e + 2], s_kp[e + 2][a], q2);
                q3 = fmaf(wq[e + 3], s_kp[e + 3][a], q3);
            }
            float g = (q0 + q1) + (q2 + q3);
            hi = bf16_rne(g);
            lo = bf16_rne(g - bf16_tof(hi));
        }
        int t = a >> 4, col = a & 15;
        int ks = d >> 5, kgrp = (d >> 3) & 3, j = d & 7;
        int fidx = (((t * 4 + ks) * 64) + (kgrp * 16 + col)) * 8 + j;
        GfB[fidx] = hi;
        GfB[FRAG_PB + fidx] = lo;
    }
}

// ---------------------------------------------------------------------------
// city row chunk -> split bf16 A-fragments (round-half-up hi, truncated lo;
// cross terms hi*lo + lo*hi captured by the 3-pass MFMA, residual ~2^-17)
// ---------------------------------------------------------------------------
__device__ __forceinline__ void load_split_A(const float* __restrict__ crp,
                                             short8* aHi, short8* aLo) {
    #pragma unroll
    for (int ks = 0; ks < 4; ++ks) {
        float4 p0 = *(const float4*)(crp + ks * 32);
        float4 p1 = *(const float4*)(crp + ks * 32 + 4);
        float f[8] = {p0.x, p0.y, p0.z, p0.w, p1.x, p1.y, p1.z, p1.w};
        short8 h, l;
        #pragma unroll
        for (int j = 0; j < 8; ++j) {
            unsigned ur = __float_as_uint(f[j]) + 0x8000u;   // round-half-up
            h[j] = (short)(ur >> 16);
            float hif = __uint_as_float(ur & 0xFFFF0000u);
            float lo  = f[j] - hif;                          // exact
            l[j] = (short)(__float_as_uint(lo) >> 16);       // truncate
        }
        aHi[ks] = h;
        aLo[ks] = l;
    }
}

// ---------------------------------------------------------------------------
// K3: MFMA split-bf16 GEMM + fused top-2 argmax, multi-tile.
// 512 threads = 8 waves x 16 cities/tile; block stages its batch's G ONCE
// (57 KB, global_load_lds, fragment order -> lane-linear conflict-free reads)
// then loops NT=5 city tiles barrier-free with A-prefetch.
// D layout: col=lane&15 (agent), row=(lane>>4)*4+reg (city).
// ---------------------------------------------------------------------------
__global__ __launch_bounds__(512, 4)
void score_mfma_kernel(const float* __restrict__ city,
                       const unsigned short* __restrict__ Gf,
                       int* __restrict__ out,
                       int* __restrict__ counter,
                       int* __restrict__ suspects) {
    const int b    = blockIdx.x / BPB;
    const int bi   = blockIdx.x % BPB;
    const int ct0  = bi * NT;
    const int tid  = threadIdx.x;
    const int wave = tid >> 6;
    const int lane = tid & 63;
    const int col  = lane & 15;
    const int kgrp = lane >> 4;

    __shared__ short8 s_frag[CHUNKS];     // 57344 B: [hi 1792 | lo 1792] chunks

    // ---- async stage G fragments (linear copy, wave-uniform LDS dest) ----
    {
        const char* gsrc = (const char*)(Gf + (size_t)b * (2 * FRAG_PB));
        #pragma unroll
        for (int it = 0; it < CHUNKS / 512; ++it) {   // 7
            int chunk = it * 512 + tid;
            __builtin_amdgcn_global_load_lds(
                (const __attribute__((address_space(1))) unsigned int*)(gsrc + (size_t)chunk * 16),
                (__attribute__((address_space(3))) unsigned int*)((char*)s_frag + (it * 512 + wave * 64) * 16),
                16, 0, 0);
        }
    }

    const float* cityb = city + (size_t)b * NCITY * DIM;

    // ---- A fragments for tile 0 (overlaps async stage) ----
    short8 aHi[4], aLo[4], nHi[4], nLo[4];
    {
        int crow = ct0 * CPB + wave * 16 + col;
        if (crow > NCITY - 1) crow = NCITY - 1;
        load_split_A(cityb + (size_t)crow * DIM + kgrp * 8, aHi, aLo);
    }

    __syncthreads();   // drains vmcnt(0): G fragments resident

    for (int it = 0; it < NT; ++it) {
        const int ct = ct0 + it;
        const int c0 = ct * CPB + wave * 16;

        // ---- GEMM: 7 n-tiles x 4 K-steps x 3 precision passes ----
        f32x4 acc[7];
        #pragma unroll
        for (int t = 0; t < 7; ++t) {
            f32x4 a4 = {0.f, 0.f, 0.f, 0.f};
            #pragma unroll
            for (int ks = 0; ks < 4; ++ks) {
                int fi = (t * 4 + ks) * 64 + lane;    // lane-linear: conflict-free
                short8 bH = s_frag[fi];
                short8 bL = s_frag[1792 + fi];
                a4 = __builtin_amdgcn_mfma_f32_16x16x32_bf16(aHi[ks], bH, a4, 0, 0, 0);
                a4 = __builtin_amdgcn_mfma_f32_16x16x32_bf16(aHi[ks], bL, a4, 0, 0, 0);
                a4 = __builtin_amdgcn_mfma_f32_16x16x32_bf16(aLo[ks], bH, a4, 0, 0, 0);
            }
            acc[t] = a4;
        }

        // ---- prefetch next tile's A fragments (hides HBM under argmax) ----
        if (it + 1 < NT) {
            int crow = (ct + 1) * CPB + wave * 16 + col;
            if (crow > NCITY - 1) crow = NCITY - 1;
            load_split_A(cityb + (size_t)crow * DIM + kgrp * 8, nHi, nLo);
        }

        // ---- fused top-2 argmax (per output row = city) ----
        #pragma unroll
        for (int r = 0; r < 4; ++r) {
            float b1 = -1e30f, b2 = -1e30f; int i1 = 0x7fffffff;
            #pragma unroll
            for (int t = 0; t < 7; ++t) {
                int a  = t * 16 + col;
                float v = (a < NAGENT) ? acc[t][r] : -1e30f;
                if (v > b1)      { b2 = b1; b1 = v; i1 = a; }
                else if (v > b2) { b2 = v; }
            }
            #pragma unroll
            for (int m = 1; m <= 8; m <<= 1) {
                float ob1 = __shfl_xor(b1, m);
                int   oi1 = __shfl_xor(i1, m);
                float ob2 = __shfl_xor(b2, m);
                if (ob1 > b1 || (ob1 == b1 && oi1 < i1)) {
                    b2 = fmaxf(b1, ob2); b1 = ob1; i1 = oi1;
                } else {
                    b2 = fmaxf(b2, ob1);
                }
            }
            if (col == 0) {
                int c = c0 + kgrp * 4 + r;        // D row = (lane>>4)*4 + reg
                if (c < NCITY) {
                    int bc = b * NCITY + c;
                    out[bc] = i1;
                    if (b1 - b2 < EPS) {
                        int s = atomicAdd(counter, 1);
                        if (s < SUSP_CAP) suspects[s] = bc;
                    }
                }
            }
        }

        if (it + 1 < NT) {
            #pragma unroll
            for (int ks = 0; ks < 4; ++ks) { aHi[ks] = nHi[ks]; aLo[ks] = nLo[ks]; }
        }
    }
}

// ---------------------------------------------------------------------------
// K4: exact fp64 re-resolution via score[a] = agent_a . (Wk @ (Wq^T c))
// [round-7-validated]
// ---------------------------------------------------------------------------
__global__ __launch_bounds__(128) void recheck_kernel(const float* __restrict__ city,
                                                      const float* __restrict__ agent,
                                                      const float* __restrict__ Wq,
                                                      const float* __restrict__ Wk,
                                                      const int* __restrict__ counter,
                                                      const int* __restrict__ suspects,
                                                      int* __restrict__ out) {
    int n = *counter;
    if (n > SUSP_CAP) n = SUSP_CAP;
    const int e = threadIdx.x;

    __shared__ float  s_c[DIM];
    __shared__ double s_q[DIM];
    __shared__ double s_r[DIM];
    __shared__ double s_best[DIM];
    __shared__ int    s_bidx[DIM];

    for (int s = blockIdx.x; s < n; s += gridDim.x) {
        const int bc = suspects[s];
        const int b  = bc / NCITY;

        s_c[e] = city[(size_t)bc * DIM + e];
        __syncthreads();

        double q = 0.0;
        #pragma unroll 8
        for (int d = 0; d < DIM; ++d)
            q += (double)s_c[d] * (double)Wq[d * DIM + e];
        s_q[e] = q;
        __syncthreads();

        double r = 0.0;
        #pragma unroll 8
        for (int k = 0; k < DIM; ++k)
            r += (double)Wk[e * DIM + k] * s_q[k];
        s_r[e] = r;
        __syncthreads();

        double best = -1.0e300;
        int    bidx = 0x7fffffff;
        if (e < NAGENT) {
            const float* ar = agent + ((size_t)b * NAGENT + e) * DIM;
            double sc = 0.0;
            #pragma unroll 8
            for (int d = 0; d < DIM; ++d)
                sc += (double)ar[d] * s_r[d];
            best = sc; bidx = e;
        }
        s_best[e] = best; s_bidx[e] = bidx;
        __syncthreads();

        for (int off = 64; off > 0; off >>= 1) {
            if (e < off) {
                double ov = s_best[e + off];
                int    oi = s_bidx[e + off];
                if (ov > s_best[e] || (ov == s_best[e] && oi < s_bidx[e])) {
                    s_best[e] = ov; s_bidx[e] = oi;
                }
            }
            __syncthreads();
        }
        if (e == 0) out[bc] = s_bidx[0];
        __syncthreads();
    }
}

// ---------------------------------------------------------------------------
extern "C" void kernel_launch(void* const* d_in, const int* in_sizes, int n_in,
                              void* d_out, int out_size, void* d_ws, size_t ws_size,
                              hipStream_t stream) {
    const float* agent = (const float*)d_in[0];   // [B, NA, D]
    const float* city  = (const float*)d_in[1];   // [B, NC, D]
    const float* Wq    = (const float*)d_in[2];   // [D, D]
    const float* Wk    = (const float*)d_in[3];   // [D, D]
    int* out = (int*)d_out;                       // [B, NC]

    char*           ws       = (char*)d_ws;
    int*            counter  = (int*)(ws + OFF_CNT);
    int*            suspects = (int*)(ws + OFF_SUS);
    float*          kp32     = (float*)(ws + OFF_KP);
    unsigned short* Gf       = (unsigned short*)(ws + OFF_GF);

    proj_k_kernel<<<NBATCH * NAGENT, DIM, 0, stream>>>(agent, Wk, kp32, counter);
    gmat_kernel<<<NBATCH * 8, 256, 0, stream>>>(Wq, kp32, Gf);
    score_mfma_kernel<<<NBATCH * BPB, 512, 0, stream>>>(city, Gf, out, counter, suspects);
    recheck_kernel<<<1024, DIM, 0, stream>>>(city, agent, Wq, Wk, counter, suspects, out);
}

// Round 11
// 217.135 us; speedup vs baseline: 1.3854x; 1.3854x over previous
//
#include <hip/hip_runtime.h>

#define DIM     128
#define NAGENT  100
#define NAP     112          // agents padded to 7x16 MFMA n-tiles
#define NCITY   5000
#define NBATCH  64
#define NA_PAD  101
#define SUSP_CAP 16384
#define EPS     2e-3f

#define CPB     128                        // cities per tile (K3)
#define CTILES  ((NCITY + CPB - 1) / CPB)  // 40
#define NT      5                          // tiles per block
#define BPB     8                          // blocks per batch (8*5 = 40 tiles)
#define FRAG_PB 14336                      // bf16 elems per batch per buffer (hi or lo)
#define CHUNKS  3584                       // 16-B chunks per batch (hi+lo)

// ---- workspace layout (bytes), total 7,012,864 ----
#define OFF_CNT 0
#define OFF_SUS 512                        // 64 KB suspect list
#define OFF_KP  66048                      // fp32 k [64][100][128] = 3,276,800
#define OFF_GF  3342848                    // bf16 Gfrag [64][ hi 14336 | lo 14336 ]

typedef __attribute__((ext_vector_type(8))) short short8;
typedef __attribute__((ext_vector_type(4))) float f32x4;

__device__ __forceinline__ unsigned short bf16_rne(float x) {
    unsigned u = __float_as_uint(x);
    u += 0x7FFFu + ((u >> 16) & 1u);
    return (unsigned short)(u >> 16);
}
__device__ __forceinline__ float bf16_tof(unsigned short h) {
    return __uint_as_float(((unsigned)h) << 16);
}

// ---------------------------------------------------------------------------
// K1: k32[b][a][e] = sum_d agent[b][a][d] * Wk[d][e]  (fp32 accum, 4-way ILP)
// Also zeroes the suspect counter (K1 -> K3 stream ordering makes this safe).
// ---------------------------------------------------------------------------
__global__ __launch_bounds__(128) void proj_k_kernel(const float* __restrict__ agent,
                                                     const float* __restrict__ Wk,
                                                     float* __restrict__ kp32,
                                                     int* __restrict__ counter) {
    const int ba = blockIdx.x;
    const int e  = threadIdx.x;

    if (ba == 0 && e == 0) *counter = 0;

    __shared__ float s_a[DIM];
    s_a[e] = agent[(size_t)ba * DIM + e];
    __syncthreads();

    float a0 = 0.f, a1 = 0.f, a2 = 0.f, a3 = 0.f;
    #pragma unroll 8
    for (int d = 0; d < DIM; d += 4) {
        a0 = fmaf(s_a[d + 0], Wk[(d + 0) * DIM + e], a0);
        a1 = fmaf(s_a[d + 1], Wk[(d + 1) * DIM + e], a1);
        a2 = fmaf(s_a[d + 2], Wk[(d + 2) * DIM + e], a2);
        a3 = fmaf(s_a[d + 3], Wk[(d + 3) * DIM + e], a3);
    }
    kp32[(size_t)ba * DIM + e] = (a0 + a1) + (a2 + a3);
}

// ---------------------------------------------------------------------------
// K2: G[b][a][d] = sum_e Wq[d][e] * k32[b][a][e] (fp32 accum, 4-way ILP),
// emitted as split bf16 (hi RNE + lo RNE) in MFMA-FRAGMENT ORDER:
//   t=a>>4, col=a&15, ks=d>>5, kgrp=(d>>3)&3, j=d&7, lane=kgrp*16+col
//   fidx = ((t*4+ks)*64 + lane)*8 + j;  pad agents [100,112) = 0.
// ---------------------------------------------------------------------------
__global__ __launch_bounds__(256) void gmat_kernel(const float* __restrict__ Wq,
                                                   const float* __restrict__ kp32,
                                                   unsigned short* __restrict__ Gf) {
    const int b      = blockIdx.x >> 3;
    const int dchunk = blockIdx.x & 7;
    const int tid    = threadIdx.x;

    __shared__ float s_kp[DIM][NA_PAD];   // [e][a]

    const float* kpb = kp32 + (size_t)b * NAGENT * DIM;
    for (int i = tid; i < NAGENT * DIM; i += 256) {
        int a = i >> 7;
        int e = i & 127;
        s_kp[e][a] = kpb[i];
    }
    __syncthreads();

    unsigned short* GfB = Gf + (size_t)b * (2 * FRAG_PB);
    const int d0 = dchunk * 16;
    for (int i = tid; i < 16 * NAP; i += 256) {   // 1792
        int dl = i / NAP;
        int a  = i - dl * NAP;
        int d  = d0 + dl;
        unsigned short hi = 0, lo = 0;
        if (a < NAGENT) {
            const float* wq = Wq + d * DIM;
            float q0 = 0.f, q1 = 0.f, q2 = 0.f, q3 = 0.f;
            #pragma unroll 8
            for (int e = 0; e < DIM; e += 4) {
                q0 = fmaf(wq[e + 0], s_kp[e + 0][a], q0);
                q1 = fmaf(wq[e + 1], s_kp[e + 1][a], q1);
                q2 = fmaf(wq[e + 2], s_kp[e + 2][a], q2);
                q3 = fmaf(wq[e + 3], s_kp[e + 3][a], q3);
            }
            float g = (q0 + q1) + (q2 + q3);
            hi = bf16_rne(g);
            lo = bf16_rne(g - bf16_tof(hi));
        }
        int t = a >> 4, col = a & 15;
        int ks = d >> 5, kgrp = (d >> 3) & 3, j = d & 7;
        int fidx = (((t * 4 + ks) * 64) + (kgrp * 16 + col)) * 8 + j;
        GfB[fidx] = hi;
        GfB[FRAG_PB + fidx] = lo;
    }
}

// ---------------------------------------------------------------------------
// city row chunk -> split bf16 A-fragments (round-half-up hi, truncated lo;
// cross terms hi*lo + lo*hi captured by the 3-pass MFMA, residual ~2^-17)
// ---------------------------------------------------------------------------
__device__ __forceinline__ void load_split_A(const float* __restrict__ crp,
                                             short8* aHi, short8* aLo) {
    #pragma unroll
    for (int ks = 0; ks < 4; ++ks) {
        float4 p0 = *(const float4*)(crp + ks * 32);
        float4 p1 = *(const float4*)(crp + ks * 32 + 4);
        float f[8] = {p0.x, p0.y, p0.z, p0.w, p1.x, p1.y, p1.z, p1.w};
        short8 h, l;
        #pragma unroll
        for (int j = 0; j < 8; ++j) {
            unsigned ur = __float_as_uint(f[j]) + 0x8000u;   // round-half-up
            h[j] = (short)(ur >> 16);
            float hif = __uint_as_float(ur & 0xFFFF0000u);
            float lo  = f[j] - hif;                          // exact
            l[j] = (short)(__float_as_uint(lo) >> 16);       // truncate
        }
        aHi[ks] = h;
        aLo[ks] = l;
    }
}

// ---------------------------------------------------------------------------
// K3: MFMA split-bf16 GEMM + fused top-2 argmax, multi-tile.
// 512 threads = 8 waves x 16 cities/tile; block stages its batch's G ONCE
// (57 KB, global_load_lds, fragment order -> lane-linear conflict-free reads)
// then loops NT=5 city tiles barrier-free with A-prefetch.
// NOTE: plain __launch_bounds__(512) — round 10's ",4" capped VGPRs at 64
// and spilled everything to scratch (FETCH 604 MB, 3x slowdown).
// D layout: col=lane&15 (agent), row=(lane>>4)*4+reg (city).
// ---------------------------------------------------------------------------
__global__ __launch_bounds__(512)
void score_mfma_kernel(const float* __restrict__ city,
                       const unsigned short* __restrict__ Gf,
                       int* __restrict__ out,
                       int* __restrict__ counter,
                       int* __restrict__ suspects) {
    const int b    = blockIdx.x / BPB;
    const int bi   = blockIdx.x % BPB;
    const int ct0  = bi * NT;
    const int tid  = threadIdx.x;
    const int wave = tid >> 6;
    const int lane = tid & 63;
    const int col  = lane & 15;
    const int kgrp = lane >> 4;

    __shared__ short8 s_frag[CHUNKS];     // 57344 B: [hi 1792 | lo 1792] chunks

    // ---- async stage G fragments (linear copy, wave-uniform LDS dest) ----
    {
        const char* gsrc = (const char*)(Gf + (size_t)b * (2 * FRAG_PB));
        #pragma unroll
        for (int it = 0; it < CHUNKS / 512; ++it) {   // 7
            int chunk = it * 512 + tid;
            __builtin_amdgcn_global_load_lds(
                (const __attribute__((address_space(1))) unsigned int*)(gsrc + (size_t)chunk * 16),
                (__attribute__((address_space(3))) unsigned int*)((char*)s_frag + (it * 512 + wave * 64) * 16),
                16, 0, 0);
        }
    }

    const float* cityb = city + (size_t)b * NCITY * DIM;

    // ---- A fragments for tile 0 (overlaps async stage) ----
    short8 aHi[4], aLo[4], nHi[4], nLo[4];
    {
        int crow = ct0 * CPB + wave * 16 + col;
        if (crow > NCITY - 1) crow = NCITY - 1;
        load_split_A(cityb + (size_t)crow * DIM + kgrp * 8, aHi, aLo);
    }

    __syncthreads();   // drains vmcnt(0): G fragments resident

    for (int it = 0; it < NT; ++it) {
        const int ct = ct0 + it;
        const int c0 = ct * CPB + wave * 16;

        // ---- GEMM: 7 n-tiles x 4 K-steps x 3 precision passes ----
        f32x4 acc[7];
        #pragma unroll
        for (int t = 0; t < 7; ++t) {
            f32x4 a4 = {0.f, 0.f, 0.f, 0.f};
            #pragma unroll
            for (int ks = 0; ks < 4; ++ks) {
                int fi = (t * 4 + ks) * 64 + lane;    // lane-linear: conflict-free
                short8 bH = s_frag[fi];
                short8 bL = s_frag[1792 + fi];
                a4 = __builtin_amdgcn_mfma_f32_16x16x32_bf16(aHi[ks], bH, a4, 0, 0, 0);
                a4 = __builtin_amdgcn_mfma_f32_16x16x32_bf16(aHi[ks], bL, a4, 0, 0, 0);
                a4 = __builtin_amdgcn_mfma_f32_16x16x32_bf16(aLo[ks], bH, a4, 0, 0, 0);
            }
            acc[t] = a4;
        }

        // ---- prefetch next tile's A fragments (hides HBM under argmax) ----
        if (it + 1 < NT) {
            int crow = (ct + 1) * CPB + wave * 16 + col;
            if (crow > NCITY - 1) crow = NCITY - 1;
            load_split_A(cityb + (size_t)crow * DIM + kgrp * 8, nHi, nLo);
        }

        // ---- fused top-2 argmax (per output row = city) ----
        #pragma unroll
        for (int r = 0; r < 4; ++r) {
            float b1 = -1e30f, b2 = -1e30f; int i1 = 0x7fffffff;
            #pragma unroll
            for (int t = 0; t < 7; ++t) {
                int a  = t * 16 + col;
                float v = (a < NAGENT) ? acc[t][r] : -1e30f;
                if (v > b1)      { b2 = b1; b1 = v; i1 = a; }
                else if (v > b2) { b2 = v; }
            }
            #pragma unroll
            for (int m = 1; m <= 8; m <<= 1) {
                float ob1 = __shfl_xor(b1, m);
                int   oi1 = __shfl_xor(i1, m);
                float ob2 = __shfl_xor(b2, m);
                if (ob1 > b1 || (ob1 == b1 && oi1 < i1)) {
                    b2 = fmaxf(b1, ob2); b1 = ob1; i1 = oi1;
                } else {
                    b2 = fmaxf(b2, ob1);
                }
            }
            if (col == 0) {
                int c = c0 + kgrp * 4 + r;        // D row = (lane>>4)*4 + reg
                if (c < NCITY) {
                    int bc = b * NCITY + c;
                    out[bc] = i1;
                    if (b1 - b2 < EPS) {
                        int s = atomicAdd(counter, 1);
                        if (s < SUSP_CAP) suspects[s] = bc;
                    }
                }
            }
        }

        if (it + 1 < NT) {
            #pragma unroll
            for (int ks = 0; ks < 4; ++ks) { aHi[ks] = nHi[ks]; aLo[ks] = nLo[ks]; }
        }
    }
}

// ---------------------------------------------------------------------------
// K4: exact fp64 re-resolution via score[a] = agent_a . (Wk @ (Wq^T c))
// [round-7-validated]
// ---------------------------------------------------------------------------
__global__ __launch_bounds__(128) void recheck_kernel(const float* __restrict__ city,
                                                      const float* __restrict__ agent,
                                                      const float* __restrict__ Wq,
                                                      const float* __restrict__ Wk,
                                                      const int* __restrict__ counter,
                                                      const int* __restrict__ suspects,
                                                      int* __restrict__ out) {
    int n = *counter;
    if (n > SUSP_CAP) n = SUSP_CAP;
    const int e = threadIdx.x;

    __shared__ float  s_c[DIM];
    __shared__ double s_q[DIM];
    __shared__ double s_r[DIM];
    __shared__ double s_best[DIM];
    __shared__ int    s_bidx[DIM];

    for (int s = blockIdx.x; s < n; s += gridDim.x) {
        const int bc = suspects[s];
        const int b  = bc / NCITY;

        s_c[e] = city[(size_t)bc * DIM + e];
        __syncthreads();

        double q = 0.0;
        #pragma unroll 8
        for (int d = 0; d < DIM; ++d)
            q += (double)s_c[d] * (double)Wq[d * DIM + e];
        s_q[e] = q;
        __syncthreads();

        double r = 0.0;
        #pragma unroll 8
        for (int k = 0; k < DIM; ++k)
            r += (double)Wk[e * DIM + k] * s_q[k];
        s_r[e] = r;
        __syncthreads();

        double best = -1.0e300;
        int    bidx = 0x7fffffff;
        if (e < NAGENT) {
            const float* ar = agent + ((size_t)b * NAGENT + e) * DIM;
            double sc = 0.0;
            #pragma unroll 8
            for (int d = 0; d < DIM; ++d)
                sc += (double)ar[d] * s_r[d];
            best = sc; bidx = e;
        }
        s_best[e] = best; s_bidx[e] = bidx;
        __syncthreads();

        for (int off = 64; off > 0; off >>= 1) {
            if (e < off) {
                double ov = s_best[e + off];
                int    oi = s_bidx[e + off];
                if (ov > s_best[e] || (ov == s_best[e] && oi < s_bidx[e])) {
                    s_best[e] = ov; s_bidx[e] = oi;
                }
            }
            __syncthreads();
        }
        if (e == 0) out[bc] = s_bidx[0];
        __syncthreads();
    }
}

// ---------------------------------------------------------------------------
extern "C" void kernel_launch(void* const* d_in, const int* in_sizes, int n_in,
                              void* d_out, int out_size, void* d_ws, size_t ws_size,
                              hipStream_t stream) {
    const float* agent = (const float*)d_in[0];   // [B, NA, D]
    const float* city  = (const float*)d_in[1];   // [B, NC, D]
    const float* Wq    = (const float*)d_in[2];   // [D, D]
    const float* Wk    = (const float*)d_in[3];   // [D, D]
    int* out = (int*)d_out;                       // [B, NC]

    char*           ws       = (char*)d_ws;
    int*            counter  = (int*)(ws + OFF_CNT);
    int*            suspects = (int*)(ws + OFF_SUS);
    float*          kp32     = (float*)(ws + OFF_KP);
    unsigned short* Gf       = (unsigned short*)(ws + OFF_GF);

    proj_k_kernel<<<NBATCH * NAGENT, DIM, 0, stream>>>(agent, Wk, kp32, counter);
    gmat_kernel<<<NBATCH * 8, 256, 0, stream>>>(Wq, kp32, Gf);
    score_mfma_kernel<<<NBATCH * BPB, 512, 0, stream>>>(city, Gf, out, counter, suspects);
    recheck_kernel<<<1024, DIM, 0, stream>>>(city, agent, Wq, Wk, counter, suspects, out);
}

// Round 12
// 171.336 us; speedup vs baseline: 1.7557x; 1.2673x over previous
//
#include <hip/hip_runtime.h>

#define DIM     128
#define NAGENT  100
#define NAP     112          // agents padded to 7x16 MFMA n-tiles
#define NCITY   5000
#define NBATCH  64
#define NA_PAD  101
#define SUSP_CAP 16384
#define EPS     2e-3f

#define CPB     128                        // cities per tile (K3)
#define CTILES  ((NCITY + CPB - 1) / CPB)  // 40
#define NT      5                          // tiles per block
#define BPB     8                          // blocks per batch (8*5 = 40 tiles)
#define FRAG_PB 14336                      // bf16 elems per batch per buffer (hi or lo)
#define CHUNKS  3584                       // 16-B chunks per batch (hi+lo)

// ---- workspace layout (bytes), total 7,012,864 ----
#define OFF_CNT 0
#define OFF_SUS 512                        // 64 KB suspect list
#define OFF_KP  66048                      // fp32 k [64][100][128] = 3,276,800
#define OFF_GF  3342848                    // bf16 Gfrag [64][ hi 14336 | lo 14336 ]

typedef __attribute__((ext_vector_type(8))) short short8;
typedef __attribute__((ext_vector_type(4))) float f32x4;

__device__ __forceinline__ unsigned short bf16_rne(float x) {
    unsigned u = __float_as_uint(x);
    u += 0x7FFFu + ((u >> 16) & 1u);
    return (unsigned short)(u >> 16);
}
__device__ __forceinline__ float bf16_tof(unsigned short h) {
    return __uint_as_float(((unsigned)h) << 16);
}

// ---------------------------------------------------------------------------
// K1: k32[b][a][e] = sum_d agent[b][a][d] * Wk[d][e]  (fp32 accum, 4-way ILP)
// Also zeroes the suspect counter (K1 -> K3 stream ordering makes this safe).
// ---------------------------------------------------------------------------
__global__ __launch_bounds__(128) void proj_k_kernel(const float* __restrict__ agent,
                                                     const float* __restrict__ Wk,
                                                     float* __restrict__ kp32,
                                                     int* __restrict__ counter) {
    const int ba = blockIdx.x;
    const int e  = threadIdx.x;

    if (ba == 0 && e == 0) *counter = 0;

    __shared__ float s_a[DIM];
    s_a[e] = agent[(size_t)ba * DIM + e];
    __syncthreads();

    float a0 = 0.f, a1 = 0.f, a2 = 0.f, a3 = 0.f;
    #pragma unroll 8
    for (int d = 0; d < DIM; d += 4) {
        a0 = fmaf(s_a[d + 0], Wk[(d + 0) * DIM + e], a0);
        a1 = fmaf(s_a[d + 1], Wk[(d + 1) * DIM + e], a1);
        a2 = fmaf(s_a[d + 2], Wk[(d + 2) * DIM + e], a2);
        a3 = fmaf(s_a[d + 3], Wk[(d + 3) * DIM + e], a3);
    }
    kp32[(size_t)ba * DIM + e] = (a0 + a1) + (a2 + a3);
}

// ---------------------------------------------------------------------------
// K2: G[b][a][d] = sum_e Wq[d][e] * k32[b][a][e] (fp32 accum, 4-way ILP),
// emitted as split bf16 (hi RNE + lo RNE) in MFMA-FRAGMENT ORDER:
//   t=a>>4, col=a&15, ks=d>>5, kgrp=(d>>3)&3, j=d&7, lane=kgrp*16+col
//   fidx = ((t*4+ks)*64 + lane)*8 + j;  pad agents [100,112) = 0.
// ---------------------------------------------------------------------------
__global__ __launch_bounds__(256) void gmat_kernel(const float* __restrict__ Wq,
                                                   const float* __restrict__ kp32,
                                                   unsigned short* __restrict__ Gf) {
    const int b      = blockIdx.x >> 3;
    const int dchunk = blockIdx.x & 7;
    const int tid    = threadIdx.x;

    __shared__ float s_kp[DIM][NA_PAD];   // [e][a]

    const float* kpb = kp32 + (size_t)b * NAGENT * DIM;
    for (int i = tid; i < NAGENT * DIM; i += 256) {
        int a = i >> 7;
        int e = i & 127;
        s_kp[e][a] = kpb[i];
    }
    __syncthreads();

    unsigned short* GfB = Gf + (size_t)b * (2 * FRAG_PB);
    const int d0 = dchunk * 16;
    for (int i = tid; i < 16 * NAP; i += 256) {   // 1792
        int dl = i / NAP;
        int a  = i - dl * NAP;
        int d  = d0 + dl;
        unsigned short hi = 0, lo = 0;
        if (a < NAGENT) {
            const float* wq = Wq + d * DIM;
            float q0 = 0.f, q1 = 0.f, q2 = 0.f, q3 = 0.f;
            #pragma unroll 8
            for (int e = 0; e < DIM; e += 4) {
                q0 = fmaf(wq[e + 0], s_kp[e + 0][a], q0);
                q1 = fmaf(wq[e + 1], s_kp[e + 1][a], q1);
                q2 = fmaf(wq[e + 2], s_kp[e + 2][a], q2);
                q3 = fmaf(wq[e + 3], s_kp[e + 3][a], q3);
            }
            float g = (q0 + q1) + (q2 + q3);
            hi = bf16_rne(g);
            lo = bf16_rne(g - bf16_tof(hi));
        }
        int t = a >> 4, col = a & 15;
        int ks = d >> 5, kgrp = (d >> 3) & 3, j = d & 7;
        int fidx = (((t * 4 + ks) * 64) + (kgrp * 16 + col)) * 8 + j;
        GfB[fidx] = hi;
        GfB[FRAG_PB + fidx] = lo;
    }
}

// ---------------------------------------------------------------------------
// city row chunk -> split bf16 A-fragments (round-half-up hi, truncated lo;
// cross terms hi*lo + lo*hi captured by the 3-pass MFMA, residual ~2^-17)
// ---------------------------------------------------------------------------
__device__ __forceinline__ void load_split_A(const float* __restrict__ crp,
                                             short8* aHi, short8* aLo) {
    #pragma unroll
    for (int ks = 0; ks < 4; ++ks) {
        float4 p0 = *(const float4*)(crp + ks * 32);
        float4 p1 = *(const float4*)(crp + ks * 32 + 4);
        float f[8] = {p0.x, p0.y, p0.z, p0.w, p1.x, p1.y, p1.z, p1.w};
        short8 h, l;
        #pragma unroll
        for (int j = 0; j < 8; ++j) {
            unsigned ur = __float_as_uint(f[j]) + 0x8000u;   // round-half-up
            h[j] = (short)(ur >> 16);
            float hif = __uint_as_float(ur & 0xFFFF0000u);
            float lo  = f[j] - hif;                          // exact
            l[j] = (short)(__float_as_uint(lo) >> 16);       // truncate
        }
        aHi[ks] = h;
        aLo[ks] = l;
    }
}

// ---------------------------------------------------------------------------
// K3: MFMA split-bf16 GEMM + fused top-2 argmax, multi-tile, NO PREFETCH.
// 512 threads = 8 waves x 16 cities/tile; block stages its batch's G ONCE
// (57 KB, global_load_lds, fragment order -> lane-linear conflict-free reads)
// then loops NT=5 city tiles barrier-free, reusing aHi/aLo each tile.
// NOTE: round 10's ",4" (VGPR cap 64) and round 11's prefetch regs (demand
// ~120 > 128 heuristic cap) both spilled to scratch — keep body <= ~100 VGPR.
// D layout: col=lane&15 (agent), row=(lane>>4)*4+reg (city).
// ---------------------------------------------------------------------------
__global__ __launch_bounds__(512)
void score_mfma_kernel(const float* __restrict__ city,
                       const unsigned short* __restrict__ Gf,
                       int* __restrict__ out,
                       int* __restrict__ counter,
                       int* __restrict__ suspects) {
    const int b    = blockIdx.x / BPB;
    const int bi   = blockIdx.x % BPB;
    const int ct0  = bi * NT;
    const int tid  = threadIdx.x;
    const int wave = tid >> 6;
    const int lane = tid & 63;
    const int col  = lane & 15;
    const int kgrp = lane >> 4;

    __shared__ short8 s_frag[CHUNKS];     // 57344 B: [hi 1792 | lo 1792] chunks

    // ---- async stage G fragments (linear copy, wave-uniform LDS dest) ----
    {
        const char* gsrc = (const char*)(Gf + (size_t)b * (2 * FRAG_PB));
        #pragma unroll
        for (int it = 0; it < CHUNKS / 512; ++it) {   // 7
            int chunk = it * 512 + tid;
            __builtin_amdgcn_global_load_lds(
                (const __attribute__((address_space(1))) unsigned int*)(gsrc + (size_t)chunk * 16),
                (__attribute__((address_space(3))) unsigned int*)((char*)s_frag + (it * 512 + wave * 64) * 16),
                16, 0, 0);
        }
    }

    const float* cityb = city + (size_t)b * NCITY * DIM;

    // ---- A fragments for tile 0 (overlaps async stage) ----
    short8 aHi[4], aLo[4];
    {
        int crow = ct0 * CPB + wave * 16 + col;
        if (crow > NCITY - 1) crow = NCITY - 1;
        load_split_A(cityb + (size_t)crow * DIM + kgrp * 8, aHi, aLo);
    }

    __syncthreads();   // drains vmcnt(0): G fragments resident

    for (int it = 0; it < NT; ++it) {
        const int ct = ct0 + it;
        const int c0 = ct * CPB + wave * 16;

        // ---- A fragments for this tile (tile 0 already loaded) ----
        if (it > 0) {
            int crow = c0 + col;
            if (crow > NCITY - 1) crow = NCITY - 1;
            load_split_A(cityb + (size_t)crow * DIM + kgrp * 8, aHi, aLo);
        }

        // ---- GEMM: 7 n-tiles x 4 K-steps x 3 precision passes ----
        f32x4 acc[7];
        #pragma unroll
        for (int t = 0; t < 7; ++t) {
            f32x4 a4 = {0.f, 0.f, 0.f, 0.f};
            #pragma unroll
            for (int ks = 0; ks < 4; ++ks) {
                int fi = (t * 4 + ks) * 64 + lane;    // lane-linear: conflict-free
                short8 bH = s_frag[fi];
                short8 bL = s_frag[1792 + fi];
                a4 = __builtin_amdgcn_mfma_f32_16x16x32_bf16(aHi[ks], bH, a4, 0, 0, 0);
                a4 = __builtin_amdgcn_mfma_f32_16x16x32_bf16(aHi[ks], bL, a4, 0, 0, 0);
                a4 = __builtin_amdgcn_mfma_f32_16x16x32_bf16(aLo[ks], bH, a4, 0, 0, 0);
            }
            acc[t] = a4;
        }

        // ---- fused top-2 argmax (per output row = city) ----
        #pragma unroll
        for (int r = 0; r < 4; ++r) {
            float b1 = -1e30f, b2 = -1e30f; int i1 = 0x7fffffff;
            #pragma unroll
            for (int t = 0; t < 7; ++t) {
                int a  = t * 16 + col;
                float v = (a < NAGENT) ? acc[t][r] : -1e30f;
                if (v > b1)      { b2 = b1; b1 = v; i1 = a; }
                else if (v > b2) { b2 = v; }
            }
            #pragma unroll
            for (int m = 1; m <= 8; m <<= 1) {
                float ob1 = __shfl_xor(b1, m);
                int   oi1 = __shfl_xor(i1, m);
                float ob2 = __shfl_xor(b2, m);
                if (ob1 > b1 || (ob1 == b1 && oi1 < i1)) {
                    b2 = fmaxf(b1, ob2); b1 = ob1; i1 = oi1;
                } else {
                    b2 = fmaxf(b2, ob1);
                }
            }
            if (col == 0) {
                int c = c0 + kgrp * 4 + r;        // D row = (lane>>4)*4 + reg
                if (c < NCITY) {
                    int bc = b * NCITY + c;
                    out[bc] = i1;
                    if (b1 - b2 < EPS) {
                        int s = atomicAdd(counter, 1);
                        if (s < SUSP_CAP) suspects[s] = bc;
                    }
                }
            }
        }
    }
}

// ---------------------------------------------------------------------------
// K4: exact fp64 re-resolution via score[a] = agent_a . (Wk @ (Wq^T c))
// [round-7-validated]
// ---------------------------------------------------------------------------
__global__ __launch_bounds__(128) void recheck_kernel(const float* __restrict__ city,
                                                      const float* __restrict__ agent,
                                                      const float* __restrict__ Wq,
                                                      const float* __restrict__ Wk,
                                                      const int* __restrict__ counter,
                                                      const int* __restrict__ suspects,
                                                      int* __restrict__ out) {
    int n = *counter;
    if (n > SUSP_CAP) n = SUSP_CAP;
    const int e = threadIdx.x;

    __shared__ float  s_c[DIM];
    __shared__ double s_q[DIM];
    __shared__ double s_r[DIM];
    __shared__ double s_best[DIM];
    __shared__ int    s_bidx[DIM];

    for (int s = blockIdx.x; s < n; s += gridDim.x) {
        const int bc = suspects[s];
        const int b  = bc / NCITY;

        s_c[e] = city[(size_t)bc * DIM + e];
        __syncthreads();

        double q = 0.0;
        #pragma unroll 8
        for (int d = 0; d < DIM; ++d)
            q += (double)s_c[d] * (double)Wq[d * DIM + e];
        s_q[e] = q;
        __syncthreads();

        double r = 0.0;
        #pragma unroll 8
        for (int k = 0; k < DIM; ++k)
            r += (double)Wk[e * DIM + k] * s_q[k];
        s_r[e] = r;
        __syncthreads();

        double best = -1.0e300;
        int    bidx = 0x7fffffff;
        if (e < NAGENT) {
            const float* ar = agent + ((size_t)b * NAGENT + e) * DIM;
            double sc = 0.0;
            #pragma unroll 8
            for (int d = 0; d < DIM; ++d)
                sc += (double)ar[d] * s_r[d];
            best = sc; bidx = e;
        }
        s_best[e] = best; s_bidx[e] = bidx;
        __syncthreads();

        for (int off = 64; off > 0; off >>= 1) {
            if (e < off) {
                double ov = s_best[e + off];
                int    oi = s_bidx[e + off];
                if (ov > s_best[e] || (ov == s_best[e] && oi < s_bidx[e])) {
                    s_best[e] = ov; s_bidx[e] = oi;
                }
            }
            __syncthreads();
        }
        if (e == 0) out[bc] = s_bidx[0];
        __syncthreads();
    }
}

// ---------------------------------------------------------------------------
extern "C" void kernel_launch(void* const* d_in, const int* in_sizes, int n_in,
                              void* d_out, int out_size, void* d_ws, size_t ws_size,
                              hipStream_t stream) {
    const float* agent = (const float*)d_in[0];   // [B, NA, D]
    const float* city  = (const float*)d_in[1];   // [B, NC, D]
    const float* Wq    = (const float*)d_in[2];   // [D, D]
    const float* Wk    = (const float*)d_in[3];   // [D, D]
    int* out = (int*)d_out;                       // [B, NC]

    char*           ws       = (char*)d_ws;
    int*            counter  = (int*)(ws + OFF_CNT);
    int*            suspects = (int*)(ws + OFF_SUS);
    float*          kp32     = (float*)(ws + OFF_KP);
    unsigned short* Gf       = (unsigned short*)(ws + OFF_GF);

    proj_k_kernel<<<NBATCH * NAGENT, DIM, 0, stream>>>(agent, Wk, kp32, counter);
    gmat_kernel<<<NBATCH * 8, 256, 0, stream>>>(Wq, kp32, Gf);
    score_mfma_kernel<<<NBATCH * BPB, 512, 0, stream>>>(city, Gf, out, counter, suspects);
    recheck_kernel<<<1024, DIM, 0, stream>>>(city, agent, Wq, Wk, counter, suspects, out);
}

// Round 13
// 145.216 us; speedup vs baseline: 2.0715x; 1.1799x over previous
//
#include <hip/hip_runtime.h>

#define DIM     128
#define NAGENT  100
#define NAP     112          // agents padded to 7x16 MFMA n-tiles
#define NCITY   5000
#define NBATCH  64
#define NA_PAD  101
#define SUSP_CAP 16384
#define EPS     2e-3f

#define CPB     128                        // cities per tile (K3)
#define CTILES  ((NCITY + CPB - 1) / CPB)  // 40
#define NT      5                          // tiles per block
#define BPB     8                          // blocks per batch (8*5 = 40 tiles)
#define FRAG_PB 14336                      // bf16 elems per batch per buffer (hi or lo)
#define CHUNKS  3584                       // 16-B chunks per batch (hi+lo)

// ---- workspace layout (bytes), total 7,012,864 ----
#define OFF_CNT 0
#define OFF_SUS 512                        // 64 KB suspect list
#define OFF_KP  66048                      // fp32 k [64][100][128] = 3,276,800
#define OFF_GF  3342848                    // bf16 Gfrag [64][ hi 14336 | lo 14336 ]

typedef __attribute__((ext_vector_type(8))) short short8;
typedef __attribute__((ext_vector_type(4))) float f32x4;

__device__ __forceinline__ unsigned short bf16_rne(float x) {
    unsigned u = __float_as_uint(x);
    u += 0x7FFFu + ((u >> 16) & 1u);
    return (unsigned short)(u >> 16);
}
__device__ __forceinline__ float bf16_tof(unsigned short h) {
    return __uint_as_float(((unsigned)h) << 16);
}

// ---------------------------------------------------------------------------
// K1: k32[b][a][e] = sum_d agent[b][a][d] * Wk[d][e]  (fp32 accum, 4-way ILP)
// Also zeroes the suspect counter (K1 -> K3 stream ordering makes this safe).
// ---------------------------------------------------------------------------
__global__ __launch_bounds__(128) void proj_k_kernel(const float* __restrict__ agent,
                                                     const float* __restrict__ Wk,
                                                     float* __restrict__ kp32,
                                                     int* __restrict__ counter) {
    const int ba = blockIdx.x;
    const int e  = threadIdx.x;

    if (ba == 0 && e == 0) *counter = 0;

    __shared__ float s_a[DIM];
    s_a[e] = agent[(size_t)ba * DIM + e];
    __syncthreads();

    float a0 = 0.f, a1 = 0.f, a2 = 0.f, a3 = 0.f;
    #pragma unroll 8
    for (int d = 0; d < DIM; d += 4) {
        a0 = fmaf(s_a[d + 0], Wk[(d + 0) * DIM + e], a0);
        a1 = fmaf(s_a[d + 1], Wk[(d + 1) * DIM + e], a1);
        a2 = fmaf(s_a[d + 2], Wk[(d + 2) * DIM + e], a2);
        a3 = fmaf(s_a[d + 3], Wk[(d + 3) * DIM + e], a3);
    }
    kp32[(size_t)ba * DIM + e] = (a0 + a1) + (a2 + a3);
}

// ---------------------------------------------------------------------------
// K2: G[b][a][d] = sum_e Wq[d][e] * k32[b][a][e] (fp32 accum, 4-way ILP),
// emitted as split bf16 (hi RNE + lo RNE) in MFMA-FRAGMENT ORDER:
//   t=a>>4, col=a&15, ks=d>>5, kgrp=(d>>3)&3, j=d&7, lane=kgrp*16+col
//   fidx = ((t*4+ks)*64 + lane)*8 + j;  pad agents [100,112) = 0.
// ---------------------------------------------------------------------------
__global__ __launch_bounds__(256) void gmat_kernel(const float* __restrict__ Wq,
                                                   const float* __restrict__ kp32,
                                                   unsigned short* __restrict__ Gf) {
    const int b      = blockIdx.x >> 3;
    const int dchunk = blockIdx.x & 7;
    const int tid    = threadIdx.x;

    __shared__ float s_kp[DIM][NA_PAD];   // [e][a]

    const float* kpb = kp32 + (size_t)b * NAGENT * DIM;
    for (int i = tid; i < NAGENT * DIM; i += 256) {
        int a = i >> 7;
        int e = i & 127;
        s_kp[e][a] = kpb[i];
    }
    __syncthreads();

    unsigned short* GfB = Gf + (size_t)b * (2 * FRAG_PB);
    const int d0 = dchunk * 16;
    for (int i = tid; i < 16 * NAP; i += 256) {   // 1792
        int dl = i / NAP;
        int a  = i - dl * NAP;
        int d  = d0 + dl;
        unsigned short hi = 0, lo = 0;
        if (a < NAGENT) {
            const float* wq = Wq + d * DIM;
            float q0 = 0.f, q1 = 0.f, q2 = 0.f, q3 = 0.f;
            #pragma unroll 8
            for (int e = 0; e < DIM; e += 4) {
                q0 = fmaf(wq[e + 0], s_kp[e + 0][a], q0);
                q1 = fmaf(wq[e + 1], s_kp[e + 1][a], q1);
                q2 = fmaf(wq[e + 2], s_kp[e + 2][a], q2);
                q3 = fmaf(wq[e + 3], s_kp[e + 3][a], q3);
            }
            float g = (q0 + q1) + (q2 + q3);
            hi = bf16_rne(g);
            lo = bf16_rne(g - bf16_tof(hi));
        }
        int t = a >> 4, col = a & 15;
        int ks = d >> 5, kgrp = (d >> 3) & 3, j = d & 7;
        int fidx = (((t * 4 + ks) * 64) + (kgrp * 16 + col)) * 8 + j;
        GfB[fidx] = hi;
        GfB[FRAG_PB + fidx] = lo;
    }
}

// ---------------------------------------------------------------------------
// city row chunk -> split bf16 A-fragments (round-half-up hi, truncated lo;
// cross terms hi*lo + lo*hi captured by the 3-pass MFMA, residual ~2^-17)
// ---------------------------------------------------------------------------
__device__ __forceinline__ void load_split_A(const float* __restrict__ crp,
                                             short8* aHi, short8* aLo) {
    #pragma unroll
    for (int ks = 0; ks < 4; ++ks) {
        float4 p0 = *(const float4*)(crp + ks * 32);
        float4 p1 = *(const float4*)(crp + ks * 32 + 4);
        float f[8] = {p0.x, p0.y, p0.z, p0.w, p1.x, p1.y, p1.z, p1.w};
        short8 h, l;
        #pragma unroll
        for (int j = 0; j < 8; ++j) {
            unsigned ur = __float_as_uint(f[j]) + 0x8000u;   // round-half-up
            h[j] = (short)(ur >> 16);
            float hif = __uint_as_float(ur & 0xFFFF0000u);
            float lo  = f[j] - hif;                          // exact
            l[j] = (short)(__float_as_uint(lo) >> 16);       // truncate
        }
        aHi[ks] = h;
        aLo[ks] = l;
    }
}

// ---------------------------------------------------------------------------
// K3: MFMA split-bf16 GEMM + fused top-2 argmax, multi-tile.
// 512 threads = 8 waves x 16 cities/tile; block stages its batch's G ONCE
// (57 KB, global_load_lds, fragment order -> lane-linear conflict-free reads)
// then loops NT=5 city tiles barrier-free, reloading aHi/aLo each tile.
// #pragma unroll 1 on the tile loop is ESSENTIAL: full unroll software-
// pipelines all 5 tiles' loads -> >128 VGPR -> scratch spill (rounds 10-12:
// WRITE_SIZE 70-148 MB, 1.4-3x slowdown). Single-iteration body = 88 VGPR
// (round 8, no spill).
// D layout: col=lane&15 (agent), row=(lane>>4)*4+reg (city).
// ---------------------------------------------------------------------------
__global__ __launch_bounds__(512)
void score_mfma_kernel(const float* __restrict__ city,
                       const unsigned short* __restrict__ Gf,
                       int* __restrict__ out,
                       int* __restrict__ counter,
                       int* __restrict__ suspects) {
    const int b    = blockIdx.x / BPB;
    const int bi   = blockIdx.x % BPB;
    const int ct0  = bi * NT;
    const int tid  = threadIdx.x;
    const int wave = tid >> 6;
    const int lane = tid & 63;
    const int col  = lane & 15;
    const int kgrp = lane >> 4;

    __shared__ short8 s_frag[CHUNKS];     // 57344 B: [hi 1792 | lo 1792] chunks

    // ---- async stage G fragments (linear copy, wave-uniform LDS dest) ----
    {
        const char* gsrc = (const char*)(Gf + (size_t)b * (2 * FRAG_PB));
        #pragma unroll
        for (int it = 0; it < CHUNKS / 512; ++it) {   // 7
            int chunk = it * 512 + tid;
            __builtin_amdgcn_global_load_lds(
                (const __attribute__((address_space(1))) unsigned int*)(gsrc + (size_t)chunk * 16),
                (__attribute__((address_space(3))) unsigned int*)((char*)s_frag + (it * 512 + wave * 64) * 16),
                16, 0, 0);
        }
    }

    const float* cityb = city + (size_t)b * NCITY * DIM;
    __syncthreads();   // drains vmcnt(0): G fragments resident

    #pragma unroll 1   // DO NOT unroll: see header comment (VGPR spill)
    for (int it = 0; it < NT; ++it) {
        const int ct = ct0 + it;
        const int c0 = ct * CPB + wave * 16;

        // ---- A fragments for this tile ----
        short8 aHi[4], aLo[4];
        {
            int crow = c0 + col;
            if (crow > NCITY - 1) crow = NCITY - 1;
            load_split_A(cityb + (size_t)crow * DIM + kgrp * 8, aHi, aLo);
        }

        // ---- GEMM: 7 n-tiles x 4 K-steps x 3 precision passes ----
        f32x4 acc[7];
        #pragma unroll
        for (int t = 0; t < 7; ++t) {
            f32x4 a4 = {0.f, 0.f, 0.f, 0.f};
            #pragma unroll
            for (int ks = 0; ks < 4; ++ks) {
                int fi = (t * 4 + ks) * 64 + lane;    // lane-linear: conflict-free
                short8 bH = s_frag[fi];
                short8 bL = s_frag[1792 + fi];
                a4 = __builtin_amdgcn_mfma_f32_16x16x32_bf16(aHi[ks], bH, a4, 0, 0, 0);
                a4 = __builtin_amdgcn_mfma_f32_16x16x32_bf16(aHi[ks], bL, a4, 0, 0, 0);
                a4 = __builtin_amdgcn_mfma_f32_16x16x32_bf16(aLo[ks], bH, a4, 0, 0, 0);
            }
            acc[t] = a4;
        }

        // ---- fused top-2 argmax (per output row = city) ----
        #pragma unroll
        for (int r = 0; r < 4; ++r) {
            float b1 = -1e30f, b2 = -1e30f; int i1 = 0x7fffffff;
            #pragma unroll
            for (int t = 0; t < 7; ++t) {
                int a  = t * 16 + col;
                float v = (a < NAGENT) ? acc[t][r] : -1e30f;
                if (v > b1)      { b2 = b1; b1 = v; i1 = a; }
                else if (v > b2) { b2 = v; }
            }
            #pragma unroll
            for (int m = 1; m <= 8; m <<= 1) {
                float ob1 = __shfl_xor(b1, m);
                int   oi1 = __shfl_xor(i1, m);
                float ob2 = __shfl_xor(b2, m);
                if (ob1 > b1 || (ob1 == b1 && oi1 < i1)) {
                    b2 = fmaxf(b1, ob2); b1 = ob1; i1 = oi1;
                } else {
                    b2 = fmaxf(b2, ob1);
                }
            }
            if (col == 0) {
                int c = c0 + kgrp * 4 + r;        // D row = (lane>>4)*4 + reg
                if (c < NCITY) {
                    int bc = b * NCITY + c;
                    out[bc] = i1;
                    if (b1 - b2 < EPS) {
                        int s = atomicAdd(counter, 1);
                        if (s < SUSP_CAP) suspects[s] = bc;
                    }
                }
            }
        }
    }
}

// ---------------------------------------------------------------------------
// K4: exact fp64 re-resolution via score[a] = agent_a . (Wk @ (Wq^T c))
// [round-7-validated]
// ---------------------------------------------------------------------------
__global__ __launch_bounds__(128) void recheck_kernel(const float* __restrict__ city,
                                                      const float* __restrict__ agent,
                                                      const float* __restrict__ Wq,
                                                      const float* __restrict__ Wk,
                                                      const int* __restrict__ counter,
                                                      const int* __restrict__ suspects,
                                                      int* __restrict__ out) {
    int n = *counter;
    if (n > SUSP_CAP) n = SUSP_CAP;
    const int e = threadIdx.x;

    __shared__ float  s_c[DIM];
    __shared__ double s_q[DIM];
    __shared__ double s_r[DIM];
    __shared__ double s_best[DIM];
    __shared__ int    s_bidx[DIM];

    for (int s = blockIdx.x; s < n; s += gridDim.x) {
        const int bc = suspects[s];
        const int b  = bc / NCITY;

        s_c[e] = city[(size_t)bc * DIM + e];
        __syncthreads();

        double q = 0.0;
        #pragma unroll 8
        for (int d = 0; d < DIM; ++d)
            q += (double)s_c[d] * (double)Wq[d * DIM + e];
        s_q[e] = q;
        __syncthreads();

        double r = 0.0;
        #pragma unroll 8
        for (int k = 0; k < DIM; ++k)
            r += (double)Wk[e * DIM + k] * s_q[k];
        s_r[e] = r;
        __syncthreads();

        double best = -1.0e300;
        int    bidx = 0x7fffffff;
        if (e < NAGENT) {
            const float* ar = agent + ((size_t)b * NAGENT + e) * DIM;
            double sc = 0.0;
            #pragma unroll 8
            for (int d = 0; d < DIM; ++d)
                sc += (double)ar[d] * s_r[d];
            best = sc; bidx = e;
        }
        s_best[e] = best; s_bidx[e] = bidx;
        __syncthreads();

        for (int off = 64; off > 0; off >>= 1) {
            if (e < off) {
                double ov = s_best[e + off];
                int    oi = s_bidx[e + off];
                if (ov > s_best[e] || (ov == s_best[e] && oi < s_bidx[e])) {
                    s_best[e] = ov; s_bidx[e] = oi;
                }
            }
            __syncthreads();
        }
        if (e == 0) out[bc] = s_bidx[0];
        __syncthreads();
    }
}

// ---------------------------------------------------------------------------
extern "C" void kernel_launch(void* const* d_in, const int* in_sizes, int n_in,
                              void* d_out, int out_size, void* d_ws, size_t ws_size,
                              hipStream_t stream) {
    const float* agent = (const float*)d_in[0];   // [B, NA, D]
    const float* city  = (const float*)d_in[1];   // [B, NC, D]
    const float* Wq    = (const float*)d_in[2];   // [D, D]
    const float* Wk    = (const float*)d_in[3];   // [D, D]
    int* out = (int*)d_out;                       // [B, NC]

    char*           ws       = (char*)d_ws;
    int*            counter  = (int*)(ws + OFF_CNT);
    int*            suspects = (int*)(ws + OFF_SUS);
    float*          kp32     = (float*)(ws + OFF_KP);
    unsigned short* Gf       = (unsigned short*)(ws + OFF_GF);

    proj_k_kernel<<<NBATCH * NAGENT, DIM, 0, stream>>>(agent, Wk, kp32, counter);
    gmat_kernel<<<NBATCH * 8, 256, 0, stream>>>(Wq, kp32, Gf);
    score_mfma_kernel<<<NBATCH * BPB, 512, 0, stream>>>(city, Gf, out, counter, suspects);
    recheck_kernel<<<1024, DIM, 0, stream>>>(city, agent, Wq, Wk, counter, suspects, out);
}

// Round 14
// 115.565 us; speedup vs baseline: 2.6030x; 1.2566x over previous
//
#include <hip/hip_runtime.h>

#define DIM     128
#define NAGENT  100
#define NAP     112          // agents padded to 7x16 MFMA n-tiles
#define NCITY   5000
#define NBATCH  64
#define NA_PAD  101
#define SUSP_CAP 16384
#define EPS     2e-3f

#define CPT     64                         // cities per block (K3): 4 waves x 16
#define TILES   ((NCITY + CPT - 1) / CPT)  // 79
#define FRAG_PB 14336                      // bf16 elems per batch per buffer (hi or lo)

// ---- workspace layout (bytes), total 7,012,864 ----
#define OFF_CNT 0
#define OFF_SUS 512                        // 64 KB suspect list
#define OFF_KP  66048                      // fp32 k [64][100][128] = 3,276,800
#define OFF_GF  3342848                    // bf16 Gfrag [64][ hi 14336 | lo 14336 ]

typedef __attribute__((ext_vector_type(8))) short short8;
typedef __attribute__((ext_vector_type(4))) float f32x4;

__device__ __forceinline__ unsigned short bf16_rne(float x) {
    unsigned u = __float_as_uint(x);
    u += 0x7FFFu + ((u >> 16) & 1u);
    return (unsigned short)(u >> 16);
}
__device__ __forceinline__ float bf16_tof(unsigned short h) {
    return __uint_as_float(((unsigned)h) << 16);
}

// ---------------------------------------------------------------------------
// K1: k32[b][a][e] = sum_d agent[b][a][d] * Wk[d][e]  (fp32 accum, 4-way ILP)
// Also zeroes the suspect counter (K1 -> K3 stream ordering makes this safe).
// ---------------------------------------------------------------------------
__global__ __launch_bounds__(128) void proj_k_kernel(const float* __restrict__ agent,
                                                     const float* __restrict__ Wk,
                                                     float* __restrict__ kp32,
                                                     int* __restrict__ counter) {
    const int ba = blockIdx.x;
    const int e  = threadIdx.x;

    if (ba == 0 && e == 0) *counter = 0;

    __shared__ float s_a[DIM];
    s_a[e] = agent[(size_t)ba * DIM + e];
    __syncthreads();

    float a0 = 0.f, a1 = 0.f, a2 = 0.f, a3 = 0.f;
    #pragma unroll 8
    for (int d = 0; d < DIM; d += 4) {
        a0 = fmaf(s_a[d + 0], Wk[(d + 0) * DIM + e], a0);
        a1 = fmaf(s_a[d + 1], Wk[(d + 1) * DIM + e], a1);
        a2 = fmaf(s_a[d + 2], Wk[(d + 2) * DIM + e], a2);
        a3 = fmaf(s_a[d + 3], Wk[(d + 3) * DIM + e], a3);
    }
    kp32[(size_t)ba * DIM + e] = (a0 + a1) + (a2 + a3);
}

// ---------------------------------------------------------------------------
// K2: G[b][a][d] = sum_e Wq[d][e] * k32[b][a][e] (fp32 accum, 4-way ILP),
// emitted as split bf16 (hi RNE + lo RNE) in MFMA-FRAGMENT ORDER:
//   t=a>>4, col=a&15, ks=d>>5, kgrp=(d>>3)&3, j=d&7, lane=kgrp*16+col
//   fidx = ((t*4+ks)*64 + lane)*8 + j;  pad agents [100,112) = 0.
// ---------------------------------------------------------------------------
__global__ __launch_bounds__(256) void gmat_kernel(const float* __restrict__ Wq,
                                                   const float* __restrict__ kp32,
                                                   unsigned short* __restrict__ Gf) {
    const int b      = blockIdx.x >> 3;
    const int dchunk = blockIdx.x & 7;
    const int tid    = threadIdx.x;

    __shared__ float s_kp[DIM][NA_PAD];   // [e][a]

    const float* kpb = kp32 + (size_t)b * NAGENT * DIM;
    for (int i = tid; i < NAGENT * DIM; i += 256) {
        int a = i >> 7;
        int e = i & 127;
        s_kp[e][a] = kpb[i];
    }
    __syncthreads();

    unsigned short* GfB = Gf + (size_t)b * (2 * FRAG_PB);
    const int d0 = dchunk * 16;
    for (int i = tid; i < 16 * NAP; i += 256) {   // 1792
        int dl = i / NAP;
        int a  = i - dl * NAP;
        int d  = d0 + dl;
        unsigned short hi = 0, lo = 0;
        if (a < NAGENT) {
            const float* wq = Wq + d * DIM;
            float q0 = 0.f, q1 = 0.f, q2 = 0.f, q3 = 0.f;
            #pragma unroll 8
            for (int e = 0; e < DIM; e += 4) {
                q0 = fmaf(wq[e + 0], s_kp[e + 0][a], q0);
                q1 = fmaf(wq[e + 1], s_kp[e + 1][a], q1);
                q2 = fmaf(wq[e + 2], s_kp[e + 2][a], q2);
                q3 = fmaf(wq[e + 3], s_kp[e + 3][a], q3);
            }
            float g = (q0 + q1) + (q2 + q3);
            hi = bf16_rne(g);
            lo = bf16_rne(g - bf16_tof(hi));
        }
        int t = a >> 4, col = a & 15;
        int ks = d >> 5, kgrp = (d >> 3) & 3, j = d & 7;
        int fidx = (((t * 4 + ks) * 64) + (kgrp * 16 + col)) * 8 + j;
        GfB[fidx] = hi;
        GfB[FRAG_PB + fidx] = lo;
    }
}

// ---------------------------------------------------------------------------
// city row chunk -> split bf16 A-fragments (round-half-up hi, truncated lo;
// cross terms hi*lo + lo*hi captured by the 3-pass MFMA, residual ~2^-17)
// ---------------------------------------------------------------------------
__device__ __forceinline__ void load_split_A(const float* __restrict__ crp,
                                             short8* aHi, short8* aLo) {
    #pragma unroll
    for (int ks = 0; ks < 4; ++ks) {
        float4 p0 = *(const float4*)(crp + ks * 32);
        float4 p1 = *(const float4*)(crp + ks * 32 + 4);
        float f[8] = {p0.x, p0.y, p0.z, p0.w, p1.x, p1.y, p1.z, p1.w};
        short8 h, l;
        #pragma unroll
        for (int j = 0; j < 8; ++j) {
            unsigned ur = __float_as_uint(f[j]) + 0x8000u;   // round-half-up
            h[j] = (short)(ur >> 16);
            float hif = __uint_as_float(ur & 0xFFFF0000u);
            float lo  = f[j] - hif;                          // exact
            l[j] = (short)(__float_as_uint(lo) >> 16);       // truncate
        }
        aHi[ks] = h;
        aLo[ks] = l;
    }
}

// ---------------------------------------------------------------------------
// K3: LDS-FREE streaming MFMA split-bf16 GEMM + fused top-2 argmax.
// 256 threads = 4 independent waves x 16 cities, NO barriers, NO LDS.
// B (G) fragments are lane-linear in global memory: gB[fi] with
// fi=(t*4+ks)*64+lane is a coalesced 1KB wave read, L2-resident (G=3.5MB).
// Top-2 update fused into the n-tile loop (no runtime-indexed acc array ->
// no scratch; rounds 10-13 spilled via acc[7]/unroll pipelining: VGPR 128,
// WRITE 44-148MB). #pragma unroll 1 keeps one n-tile's loads live at a time.
// D layout: col=lane&15 (agent), row=(lane>>4)*4+reg (city).
// ---------------------------------------------------------------------------
__global__ __launch_bounds__(256)
void score_mfma_kernel(const float* __restrict__ city,
                       const unsigned short* __restrict__ Gf,
                       int* __restrict__ out,
                       int* __restrict__ counter,
                       int* __restrict__ suspects) {
    const int b    = blockIdx.x / TILES;
    const int ct   = blockIdx.x % TILES;
    const int tid  = threadIdx.x;
    const int wave = tid >> 6;
    const int lane = tid & 63;
    const int col  = lane & 15;
    const int kgrp = lane >> 4;

    const int c0 = ct * CPT + wave * 16;
    int crow = c0 + col; if (crow > NCITY - 1) crow = NCITY - 1;

    // ---- A fragments: city rows fp32 -> split bf16 ----
    short8 aHi[4], aLo[4];
    load_split_A(city + ((size_t)b * NCITY + crow) * DIM + kgrp * 8, aHi, aLo);

    const short8* gB = (const short8*)(Gf + (size_t)b * (2 * FRAG_PB));

    // running top-2 per output row r (static-indexed scalars via full unroll)
    float B1[4] = {-1e30f, -1e30f, -1e30f, -1e30f};
    float B2[4] = {-1e30f, -1e30f, -1e30f, -1e30f};
    int   I1[4] = {0x7fffffff, 0x7fffffff, 0x7fffffff, 0x7fffffff};

    #pragma unroll 1   // DO NOT unroll: hoisted loads -> VGPR spill (r10-13)
    for (int t = 0; t < 7; ++t) {
        f32x4 a4 = {0.f, 0.f, 0.f, 0.f};
        #pragma unroll
        for (int ks = 0; ks < 4; ++ks) {
            int fi = (t * 4 + ks) * 64 + lane;   // coalesced 1KB wave read (L2)
            short8 bH = gB[fi];
            short8 bL = gB[1792 + fi];
            a4 = __builtin_amdgcn_mfma_f32_16x16x32_bf16(aHi[ks], bH, a4, 0, 0, 0);
            a4 = __builtin_amdgcn_mfma_f32_16x16x32_bf16(aHi[ks], bL, a4, 0, 0, 0);
            a4 = __builtin_amdgcn_mfma_f32_16x16x32_bf16(aLo[ks], bH, a4, 0, 0, 0);
        }
        const int a = t * 16 + col;              // ascending -> tie-break kept
        const bool va = (a < NAGENT);
        #pragma unroll
        for (int r = 0; r < 4; ++r) {
            float v = va ? a4[r] : -1e30f;
            if (v > B1[r])      { B2[r] = B1[r]; B1[r] = v; I1[r] = a; }
            else if (v > B2[r]) { B2[r] = v; }
        }
    }

    // ---- butterfly merge across the 16 agent-columns ----
    #pragma unroll
    for (int r = 0; r < 4; ++r) {
        float b1 = B1[r], b2 = B2[r]; int i1 = I1[r];
        #pragma unroll
        for (int m = 1; m <= 8; m <<= 1) {
            float ob1 = __shfl_xor(b1, m);
            int   oi1 = __shfl_xor(i1, m);
            float ob2 = __shfl_xor(b2, m);
            if (ob1 > b1 || (ob1 == b1 && oi1 < i1)) {
                b2 = fmaxf(b1, ob2); b1 = ob1; i1 = oi1;
            } else {
                b2 = fmaxf(b2, ob1);
            }
        }
        if (col == 0) {
            int c = c0 + kgrp * 4 + r;           // D row = (lane>>4)*4 + reg
            if (c < NCITY) {
                int bc = b * NCITY + c;
                out[bc] = i1;
                if (b1 - b2 < EPS) {
                    int s = atomicAdd(counter, 1);
                    if (s < SUSP_CAP) suspects[s] = bc;
                }
            }
        }
    }
}

// ---------------------------------------------------------------------------
// K4: exact fp64 re-resolution via score[a] = agent_a . (Wk @ (Wq^T c))
// [round-7-validated]
// ---------------------------------------------------------------------------
__global__ __launch_bounds__(128) void recheck_kernel(const float* __restrict__ city,
                                                      const float* __restrict__ agent,
                                                      const float* __restrict__ Wq,
                                                      const float* __restrict__ Wk,
                                                      const int* __restrict__ counter,
                                                      const int* __restrict__ suspects,
                                                      int* __restrict__ out) {
    int n = *counter;
    if (n > SUSP_CAP) n = SUSP_CAP;
    const int e = threadIdx.x;

    __shared__ float  s_c[DIM];
    __shared__ double s_q[DIM];
    __shared__ double s_r[DIM];
    __shared__ double s_best[DIM];
    __shared__ int    s_bidx[DIM];

    for (int s = blockIdx.x; s < n; s += gridDim.x) {
        const int bc = suspects[s];
        const int b  = bc / NCITY;

        s_c[e] = city[(size_t)bc * DIM + e];
        __syncthreads();

        double q = 0.0;
        #pragma unroll 8
        for (int d = 0; d < DIM; ++d)
            q += (double)s_c[d] * (double)Wq[d * DIM + e];
        s_q[e] = q;
        __syncthreads();

        double r = 0.0;
        #pragma unroll 8
        for (int k = 0; k < DIM; ++k)
            r += (double)Wk[e * DIM + k] * s_q[k];
        s_r[e] = r;
        __syncthreads();

        double best = -1.0e300;
        int    bidx = 0x7fffffff;
        if (e < NAGENT) {
            const float* ar = agent + ((size_t)b * NAGENT + e) * DIM;
            double sc = 0.0;
            #pragma unroll 8
            for (int d = 0; d < DIM; ++d)
                sc += (double)ar[d] * s_r[d];
            best = sc; bidx = e;
        }
        s_best[e] = best; s_bidx[e] = bidx;
        __syncthreads();

        for (int off = 64; off > 0; off >>= 1) {
            if (e < off) {
                double ov = s_best[e + off];
                int    oi = s_bidx[e + off];
                if (ov > s_best[e] || (ov == s_best[e] && oi < s_bidx[e])) {
                    s_best[e] = ov; s_bidx[e] = oi;
                }
            }
            __syncthreads();
        }
        if (e == 0) out[bc] = s_bidx[0];
        __syncthreads();
    }
}

// ---------------------------------------------------------------------------
extern "C" void kernel_launch(void* const* d_in, const int* in_sizes, int n_in,
                              void* d_out, int out_size, void* d_ws, size_t ws_size,
                              hipStream_t stream) {
    const float* agent = (const float*)d_in[0];   // [B, NA, D]
    const float* city  = (const float*)d_in[1];   // [B, NC, D]
    const float* Wq    = (const float*)d_in[2];   // [D, D]
    const float* Wk    = (const float*)d_in[3];   // [D, D]
    int* out = (int*)d_out;                       // [B, NC]

    char*           ws       = (char*)d_ws;
    int*            counter  = (int*)(ws + OFF_CNT);
    int*            suspects = (int*)(ws + OFF_SUS);
    float*          kp32     = (float*)(ws + OFF_KP);
    unsigned short* Gf       = (unsigned short*)(ws + OFF_GF);

    proj_k_kernel<<<NBATCH * NAGENT, DIM, 0, stream>>>(agent, Wk, kp32, counter);
    gmat_kernel<<<NBATCH * 8, 256, 0, stream>>>(Wq, kp32, Gf);
    score_mfma_kernel<<<NBATCH * TILES, 256, 0, stream>>>(city, Gf, out, counter, suspects);
    recheck_kernel<<<1024, DIM, 0, stream>>>(city, agent, Wq, Wk, counter, suspects, out);
}